// Round 8
// baseline (156.190 us; speedup 1.0000x reference)
//
#include <hip/hip_runtime.h>
#include <math.h>

#define BLOCK 256
#define GRID 2048
#define FBLOCK 1024
#define NTRIP 8   // float4 trips per thread on the fast path (N = 2^24)

__device__ __forceinline__ void gload_lds16(const float4* g, float4* l) {
    // async DMA: global (per-lane addr) -> LDS (wave-uniform base + lane*16)
    __builtin_amdgcn_global_load_lds(
        (const __attribute__((address_space(1))) void*)g,
        (__attribute__((address_space(3))) void*)l,
        16, 0, 0);
}

__global__ __launch_bounds__(BLOCK) void ratledge_partial(
    const float* __restrict__ yp, const float* __restrict__ yt,
    const float* __restrict__ quants, float* __restrict__ partial, int n)
{
    __shared__ float4 lA[3][BLOCK];   // 3-deep rotation, 4 KB per buf
    __shared__ float4 lB[3][BLOCK];

    float q[6];
#pragma unroll
    for (int j = 0; j < 6; ++j) q[j] = quants[j];
    const float q5 = q[5];

    float msum = 0.f;
    // suffix accumulators: ss[j] = sum of d over {q_j <= v <= q5}; sc[j] = count
    float ss[5] = {0.f, 0.f, 0.f, 0.f, 0.f};
    float sc[5] = {0.f, 0.f, 0.f, 0.f, 0.f};

    const int tid    = blockIdx.x * BLOCK + threadIdx.x;
    const int stride = GRID * BLOCK;
    const int n4     = n >> 2;
    const float4* yp4 = (const float4*)yp;
    const float4* yt4 = (const float4*)yt;

    auto body1 = [&](float p, float v) {
        float d = p - v;
        msum = fmaf(d, d, msum);
        // invalid-high (v > q5, incl. NaN) -> -inf fails every v>=q_j test.
        // v == q5 passes all 5 -> bin 4 via differencing. Exact
        // searchsorted(side='right') semantics.
        float vv = (v <= q5) ? v : -INFINITY;
#pragma unroll
        for (int j = 0; j < 5; ++j) {
            bool m = (vv >= q[j]);
            ss[j] += m ? d   : 0.f;
            sc[j] += m ? 1.f : 0.f;
        }
    };
    auto body4 = [&](const float4& p, const float4& t) {
        body1(p.x, t.x); body1(p.y, t.y); body1(p.z, t.z); body1(p.w, t.w);
    };

    if (n == stride * (4 * NTRIP)) {
        // ===== fast path: DMA-to-LDS pipeline, depth 2, counted vmcnt =====
        const int tx    = threadIdx.x;
        const int wbase = tx & ~63;            // wave-uniform slice base (wid*64)
        const float4* gA = yp4 + tid;
        const float4* gB = yt4 + tid;

        // prologue: stage trips 0,1,2
#pragma unroll
        for (int k = 0; k < 3; ++k) {
            gload_lds16(gA + k * stride, &lA[k][wbase]);
            gload_lds16(gB + k * stride, &lB[k][wbase]);
        }

#pragma unroll
        for (int k = 0; k < NTRIP; ++k) {
            // wait for trip k's 2 loads; keep newer trips in flight
            if (k <= NTRIP - 3)      asm volatile("s_waitcnt vmcnt(4)" ::: "memory");
            else if (k == NTRIP - 2) asm volatile("s_waitcnt vmcnt(2)" ::: "memory");
            else                     asm volatile("s_waitcnt vmcnt(0)" ::: "memory");
            __builtin_amdgcn_sched_barrier(0);

            // read own slice (no cross-wave sharing -> no barriers)
            float4 pv = lA[k % 3][tx];
            float4 tv = lB[k % 3][tx];
            asm volatile("s_waitcnt lgkmcnt(0)" ::: "memory");
            __builtin_amdgcn_sched_barrier(0);

            // refill the buffer we just drained (overlaps with compute below)
            if (k + 3 < NTRIP) {
                gload_lds16(gA + (k + 3) * stride, &lA[k % 3][wbase]);
                gload_lds16(gB + (k + 3) * stride, &lB[k % 3][wbase]);
            }

            body4(pv, tv);
        }
    } else {
        // ===== generic path (any n) =====
        const int trips = n4 / stride;
        for (int k = 0; k < trips; ++k) {
            const int i = tid + k * stride;
            float4 p = yp4[i];
            float4 t = yt4[i];
            body4(p, t);
        }
        const int i = tid + trips * stride;
        if (i < n4) {
            float4 p = yp4[i];
            float4 t = yt4[i];
            body4(p, t);
        }
        for (int i2 = (n4 << 2) + tid; i2 < n; i2 += stride)
            body1(yp[i2], yt[i2]);
    }

    // wave64 shuffle reduce of 11 partials
    float vals[11];
    vals[0] = msum;
#pragma unroll
    for (int j = 0; j < 5; ++j) { vals[1 + j] = ss[j]; vals[6 + j] = sc[j]; }
#pragma unroll
    for (int off = 32; off > 0; off >>= 1) {
#pragma unroll
        for (int j = 0; j < 11; ++j)
            vals[j] += __shfl_down(vals[j], off, 64);
    }

    __shared__ float sred[BLOCK / 64][11];
    const int lane = threadIdx.x & 63;
    const int wid  = threadIdx.x >> 6;
    if (lane == 0) {
#pragma unroll
        for (int j = 0; j < 11; ++j) sred[wid][j] = vals[j];
    }
    __syncthreads();
    if (threadIdx.x == 0) {
#pragma unroll
        for (int j = 0; j < 11; ++j) {
            float s = sred[0][j] + sred[1][j] + sred[2][j] + sred[3][j];
            partial[j * GRID + blockIdx.x] = s;  // SoA: coalesced in finalize
        }
    }
}

__global__ __launch_bounds__(FBLOCK) void ratledge_final(
    const float* __restrict__ partial, float* __restrict__ out, int n)
{
    const int t    = threadIdx.x;
    const int lane = t & 63;
    const int wid  = t >> 6;   // 0..15

    double acc[11];
#pragma unroll
    for (int j = 0; j < 11; ++j) {
        float a0 = partial[j * GRID + t];
        float a1 = partial[j * GRID + t + FBLOCK];
        acc[j] = (double)a0 + (double)a1;
    }

#pragma unroll
    for (int off = 32; off > 0; off >>= 1) {
#pragma unroll
        for (int j = 0; j < 11; ++j)
            acc[j] += __shfl_down(acc[j], off, 64);
    }

    __shared__ double sred[FBLOCK / 64][11];
    if (lane == 0) {
#pragma unroll
        for (int j = 0; j < 11; ++j) sred[wid][j] = acc[j];
    }
    __syncthreads();

    if (wid == 0) {
        double v[11];
#pragma unroll
        for (int j = 0; j < 11; ++j)
            v[j] = (lane < FBLOCK / 64) ? sred[lane][j] : 0.0;
#pragma unroll
        for (int off = 8; off > 0; off >>= 1) {
#pragma unroll
            for (int j = 0; j < 11; ++j)
                v[j] += __shfl_down(v[j], off, 64);
        }
        if (lane == 0) {
            double mse = v[0] / (double)n;
            double maxb2 = 0.0;  // torch starts from tensor(0.0)
            // un-difference the suffix accumulators: bin j = suffix j - suffix j+1
#pragma unroll
            for (int j = 0; j < 5; ++j) {
                double Sj  = v[1 + j];
                double Sj1 = (j < 4) ? v[2 + j] : 0.0;
                double Cj  = v[6 + j];
                double Cj1 = (j < 4) ? v[7 + j] : 0.0;
                double cnt = Cj - Cj1;
                double sum = Sj - Sj1;
                double bias = sum / fmax(cnt, 1.0);
                double b2   = (cnt > 0.0) ? bias * bias : 0.0;
                maxb2 = fmax(maxb2, b2);
            }
            out[0] = (float)(mse + 5.0 * maxb2);
        }
    }
}

extern "C" void kernel_launch(void* const* d_in, const int* in_sizes, int n_in,
                              void* d_out, int out_size, void* d_ws, size_t ws_size,
                              hipStream_t stream) {
    const float* yp = (const float*)d_in[0];
    const float* yt = (const float*)d_in[1];
    const float* q  = (const float*)d_in[2];
    float* partial  = (float*)d_ws;          // GRID*11*4 = 90112 B
    float* out      = (float*)d_out;
    int n = in_sizes[0];

    ratledge_partial<<<GRID, BLOCK, 0, stream>>>(yp, yt, q, partial, n);
    ratledge_final<<<1, FBLOCK, 0, stream>>>(partial, out, n);
}

// Round 9
// 155.179 us; speedup vs baseline: 1.0065x; 1.0065x over previous
//
#include <hip/hip_runtime.h>
#include <math.h>

#define BLOCK 256
#define GRID 2048
#define FBLOCK 1024
#define NTRIP 8   // float4 trips per thread on the fast path (N = 2^24)
#define ROT 48    // B-stream lane rotation: 48 lanes * 16B = 768B (flips addr bits 8-9)

__global__ __launch_bounds__(BLOCK) void ratledge_partial(
    const float* __restrict__ yp, const float* __restrict__ yt,
    const float* __restrict__ quants, float* __restrict__ partial, int n)
{
    float q[6];
#pragma unroll
    for (int j = 0; j < 6; ++j) q[j] = quants[j];
    const float q5 = q[5];

    float msum = 0.f;
    // suffix accumulators: ss[j] = sum of d over {q_j <= v <= q5}; sc[j] = count
    float ss[5] = {0.f, 0.f, 0.f, 0.f, 0.f};
    float sc[5] = {0.f, 0.f, 0.f, 0.f, 0.f};

    const int tid    = blockIdx.x * BLOCK + threadIdx.x;
    const int stride = GRID * BLOCK;
    const int n4     = n >> 2;
    const float4* yp4 = (const float4*)yp;
    const float4* yt4 = (const float4*)yt;

    auto body1 = [&](float p, float v) {
        float d = p - v;
        msum = fmaf(d, d, msum);
        // invalid-high (v > q5, incl. NaN) -> -inf fails every v>=q_j test.
        // v == q5 passes all 5 -> bin 4 via differencing. Exact
        // searchsorted(side='right') semantics.
        float vv = (v <= q5) ? v : -INFINITY;
#pragma unroll
        for (int j = 0; j < 5; ++j) {
            bool m = (vv >= q[j]);
            ss[j] += m ? d   : 0.f;
            sc[j] += m ? 1.f : 0.f;
        }
    };
    auto body4 = [&](const float4& p, const float4& t) {
        body1(p.x, t.x); body1(p.y, t.y); body1(p.z, t.z); body1(p.w, t.w);
    };

    if (n == stride * (4 * NTRIP)) {
        // ===== fast path =====
        // yp and yt are 64MB apart (pow2): A@X and B@X share channel+bank bits.
        // Decorrelate: lane l fetches B from slot (l+ROT)&63 of its wave's
        // 1KB chunk (+768B -> different channel/bank), then un-rotate with
        // shuffles. Pure permutation + inverse: bit-exact.
        const int lane   = threadIdx.x & 63;
        const int rotTid = (tid & ~63) | ((lane + ROT) & 63);
        const int unrot  = (lane + (64 - ROT)) & 63;   // src lane holding my B

#pragma unroll
        for (int k = 0; k < NTRIP; ++k) {
            float4 p = yp4[tid + k * stride];
            float4 braw = yt4[rotTid + k * stride];
            float4 t;
            t.x = __shfl(braw.x, unrot, 64);
            t.y = __shfl(braw.y, unrot, 64);
            t.z = __shfl(braw.z, unrot, 64);
            t.w = __shfl(braw.w, unrot, 64);
            body4(p, t);
        }
    } else {
        // ===== generic path (any n) =====
        const int trips = n4 / stride;
        for (int k = 0; k < trips; ++k) {
            const int i = tid + k * stride;
            float4 p = yp4[i];
            float4 t = yt4[i];
            body4(p, t);
        }
        const int i = tid + trips * stride;
        if (i < n4) {
            float4 p = yp4[i];
            float4 t = yt4[i];
            body4(p, t);
        }
        for (int i2 = (n4 << 2) + tid; i2 < n; i2 += stride)
            body1(yp[i2], yt[i2]);
    }

    // wave64 shuffle reduce of 11 partials
    float vals[11];
    vals[0] = msum;
#pragma unroll
    for (int j = 0; j < 5; ++j) { vals[1 + j] = ss[j]; vals[6 + j] = sc[j]; }
#pragma unroll
    for (int off = 32; off > 0; off >>= 1) {
#pragma unroll
        for (int j = 0; j < 11; ++j)
            vals[j] += __shfl_down(vals[j], off, 64);
    }

    __shared__ float sred[BLOCK / 64][11];
    const int lane = threadIdx.x & 63;
    const int wid  = threadIdx.x >> 6;
    if (lane == 0) {
#pragma unroll
        for (int j = 0; j < 11; ++j) sred[wid][j] = vals[j];
    }
    __syncthreads();
    if (threadIdx.x == 0) {
#pragma unroll
        for (int j = 0; j < 11; ++j) {
            float s = sred[0][j] + sred[1][j] + sred[2][j] + sred[3][j];
            partial[j * GRID + blockIdx.x] = s;  // SoA: coalesced in finalize
        }
    }
}

__global__ __launch_bounds__(FBLOCK) void ratledge_final(
    const float* __restrict__ partial, float* __restrict__ out, int n)
{
    const int t    = threadIdx.x;
    const int lane = t & 63;
    const int wid  = t >> 6;   // 0..15

    double acc[11];
#pragma unroll
    for (int j = 0; j < 11; ++j) {
        float a0 = partial[j * GRID + t];
        float a1 = partial[j * GRID + t + FBLOCK];
        acc[j] = (double)a0 + (double)a1;
    }

#pragma unroll
    for (int off = 32; off > 0; off >>= 1) {
#pragma unroll
        for (int j = 0; j < 11; ++j)
            acc[j] += __shfl_down(acc[j], off, 64);
    }

    __shared__ double sred[FBLOCK / 64][11];
    if (lane == 0) {
#pragma unroll
        for (int j = 0; j < 11; ++j) sred[wid][j] = acc[j];
    }
    __syncthreads();

    if (wid == 0) {
        double v[11];
#pragma unroll
        for (int j = 0; j < 11; ++j)
            v[j] = (lane < FBLOCK / 64) ? sred[lane][j] : 0.0;
#pragma unroll
        for (int off = 8; off > 0; off >>= 1) {
#pragma unroll
            for (int j = 0; j < 11; ++j)
                v[j] += __shfl_down(v[j], off, 64);
        }
        if (lane == 0) {
            double mse = v[0] / (double)n;
            double maxb2 = 0.0;  // torch starts from tensor(0.0)
            // un-difference the suffix accumulators: bin j = suffix j - suffix j+1
#pragma unroll
            for (int j = 0; j < 5; ++j) {
                double Sj  = v[1 + j];
                double Sj1 = (j < 4) ? v[2 + j] : 0.0;
                double Cj  = v[6 + j];
                double Cj1 = (j < 4) ? v[7 + j] : 0.0;
                double cnt = Cj - Cj1;
                double sum = Sj - Sj1;
                double bias = sum / fmax(cnt, 1.0);
                double b2   = (cnt > 0.0) ? bias * bias : 0.0;
                maxb2 = fmax(maxb2, b2);
            }
            out[0] = (float)(mse + 5.0 * maxb2);
        }
    }
}

extern "C" void kernel_launch(void* const* d_in, const int* in_sizes, int n_in,
                              void* d_out, int out_size, void* d_ws, size_t ws_size,
                              hipStream_t stream) {
    const float* yp = (const float*)d_in[0];
    const float* yt = (const float*)d_in[1];
    const float* q  = (const float*)d_in[2];
    float* partial  = (float*)d_ws;          // GRID*11*4 = 90112 B
    float* out      = (float*)d_out;
    int n = in_sizes[0];

    ratledge_partial<<<GRID, BLOCK, 0, stream>>>(yp, yt, q, partial, n);
    ratledge_final<<<1, FBLOCK, 0, stream>>>(partial, out, n);
}